// Round 8
// baseline (192.028 us; speedup 1.0000x reference)
//
#include <hip/hip_runtime.h>
#include <cstddef>

#define N_NODES_C 50000
#define N_NODES_PAD 50048
#define N_EDGES_C 800000

typedef _Float16 f16x8 __attribute__((ext_vector_type(8)));
typedef float    f32x4 __attribute__((ext_vector_type(4)));

constexpr int XSTR = 72;           // f16 stride for per-wave h buffer
constexpr int MQ_BLOCKS   = 782;   // ceil(50000/64) compute blocks
constexpr int FILL_BLOCKS = 782;   // ceil(800000/1024), 4 edges/thread
constexpr int DEG_BLOCKS  = 782;   // ceil(800000/1024), 4 edges/thread

// global -> LDS direct copy, 16B per lane. lds ptr must be wave-uniform base;
// HW writes base + lane*16. global ptr is per-lane.
__device__ __forceinline__ void gll16(const void* g, void* l) {
    __builtin_amdgcn_global_load_lds(
        (const __attribute__((address_space(1))) void*)g,
        (__attribute__((address_space(3))) void*)l, 16, 0, 0);
}

// ---------------------------------------------------------------------------
// prep (wT, W3T swizzled) + deg fused (4 shadow arrays, 4 edges/thread).
//  wT[l][j][k] = W_l[k][j] (f16)                      idx [0, 28672)
//  W3T[r=y*64+x][64 k] (f16), 16B chunks XOR-swizzled: chunk c of row r
//  stored at chunk c^(r&7). Value = w_out[k*2048 + r].
//  Coalesced-read mapping (transpose scatter on the write side).
//  Deg pass captures rank[e] = old count in shadow k = (e>>8)&3 —
//  makes the CSR fill atomic-free (slot = shoff[k][col] + rank[e]).
// ---------------------------------------------------------------------------
__global__ void prep_deg_kernel(const float* __restrict__ w_in,
                                const float* __restrict__ w_mid,
                                const float* __restrict__ w_out,
                                const int* __restrict__ col,
                                _Float16* __restrict__ wT,
                                _Float16* __restrict__ W3T,
                                int* __restrict__ deg4,   // [4][N_NODES_C]
                                int* __restrict__ rank)   // [N_EDGES_C]
{
    const int b = blockIdx.x;
    if (b < 624) {
        const int idx = b * 256 + threadIdx.x;
        if (idx < 7 * 4096) {
            const int l = idx >> 12, rem = idx & 4095;
            const int k = rem >> 6, j = rem & 63;      // lanes: consecutive j
            const float v = (l == 0) ? w_in[k * 64 + j]
                                     : w_mid[(size_t)(l - 1) * 4096 + k * 64 + j];
            wT[(size_t)l * 4096 + j * 64 + k] = (_Float16)v;
        } else {
            const int i2 = idx - 7 * 4096;             // < 131072
            const int k = i2 >> 11, r = i2 & 2047;     // lanes: consecutive r
            const int c = k >> 3;
            const int pos = ((c ^ (r & 7)) << 3) | (k & 7);
            W3T[(size_t)r * 64 + pos] = (_Float16)w_out[(size_t)k * 2048 + r];
        }
    } else {
        const int e0 = (b - 624) * 1024 + threadIdx.x;
        #pragma unroll
        for (int k = 0; k < 4; ++k) {
            const int e = e0 + k * 256;
            if (e < N_EDGES_C)
                rank[e] = atomicAdd(&deg4[k * N_NODES_C + col[e]], 1);
        }
    }
}

// ---------------------------------------------------------------------------
// 3-phase parallel scan; scan3 also emits dinv and per-shadow offsets shoff.
// ---------------------------------------------------------------------------
__global__ void scan1_kernel(const int* __restrict__ deg4, int* __restrict__ bsum)
{
    const int t = threadIdx.x;
    const int i = blockIdx.x * 256 + t;
    int v = 0;
    if (i < N_NODES_C) {
        #pragma unroll
        for (int k = 0; k < 4; ++k) v += deg4[k * N_NODES_C + i];
    }
    #pragma unroll
    for (int d = 1; d < 64; d <<= 1) v += __shfl_xor(v, d);
    __shared__ int s[4];
    if ((t & 63) == 0) s[t >> 6] = v;
    __syncthreads();
    if (t == 0) bsum[blockIdx.x] = s[0] + s[1] + s[2] + s[3];
}

__global__ void scan2_kernel(const int* __restrict__ bsum, int* __restrict__ boff,
                             int* __restrict__ rowptr)
{
    __shared__ int sh[256];
    const int t = threadIdx.x;
    const int v = (t < 196) ? bsum[t] : 0;
    sh[t] = v;
    __syncthreads();
    for (int d = 1; d < 256; d <<= 1) {
        const int u = (t >= d) ? sh[t - d] : 0;
        __syncthreads();
        sh[t] += u;
        __syncthreads();
    }
    if (t < 196) boff[t] = sh[t] - v;     // exclusive
    if (t == 0) rowptr[N_NODES_C] = N_EDGES_C;
}

__global__ void scan3_kernel(const int* __restrict__ deg4, const int* __restrict__ boff,
                             int* __restrict__ rowptr, int* __restrict__ shoff,
                             float* __restrict__ dinv)
{
    const int t = threadIdx.x;
    const int i = blockIdx.x * 256 + t;
    const int lane = t & 63, w = t >> 6;
    int d[4];
    int v = 0;
    if (i < N_NODES_C) {
        #pragma unroll
        for (int k = 0; k < 4; ++k) { d[k] = deg4[k * N_NODES_C + i]; v += d[k]; }
    } else {
        d[0] = d[1] = d[2] = d[3] = 0;
    }
    int inc = v;
    #pragma unroll
    for (int dd = 1; dd < 64; dd <<= 1) {
        const int u = __shfl_up(inc, dd);
        if (lane >= dd) inc += u;
    }
    __shared__ int ws[4];
    if (lane == 63) ws[w] = inc;
    __syncthreads();
    int wo = 0;
    #pragma unroll
    for (int k = 0; k < 4; ++k) if (k < w) wo += ws[k];
    const int excl = boff[blockIdx.x] + wo + inc - v;
    if (i < N_NODES_C) {
        rowptr[i] = excl;
        dinv[i] = (v > 0) ? rsqrtf((float)v) : 0.f;
        int o = excl;
        shoff[0 * N_NODES_C + i] = o; o += d[0];
        shoff[1 * N_NODES_C + i] = o; o += d[1];
        shoff[2 * N_NODES_C + i] = o; o += d[2];
        shoff[3 * N_NODES_C + i] = o;
    }
}

// ---------------------------------------------------------------------------
// MEGA kernel: compute blocks first, fill blocks after.
//  Compute blocks: 64 nodes, 4 waves.
//   Phase 1: per-wave MLP, 16 nodes/wave (unchanged).
//   Phase 2: SLICE-PER-WAVE. Wave w owns y = 4*yy + w (8 slices) and computes
//   ALL 64 nodes per slice (4 h-sets in regs). Each A-fragment read feeds 4
//   MFMAs -> 4x less LDS read than wave-per-node-group. Each wave stages its
//   own slices into a PRIVATE 2-slot LDS ring via global_load_lds -> ZERO
//   barriers in the loop; sync = wave-private counted vmcnt.
//   Ledger (per wave): prologue = bout(2 gll) s0(8) s1(8); vmcnt(16) + raw
//   barrier (bout cross-wave visible). Loop yy: wait slot (vmcnt 8/9/1 at
//   yy=0/mid/7), compute 32 MFMA, store 1, lgkmcnt(0), refill same slot with
//   slice yy+2 (8 gll).
// ---------------------------------------------------------------------------
__launch_bounds__(256, 2)
__global__ void mega_kernel(const float* __restrict__ xf,
                            const float* __restrict__ b_in,
                            const float* __restrict__ b_mid,
                            const _Float16* __restrict__ wT,
                            const _Float16* __restrict__ W3T,
                            const float* __restrict__ b_out,
                            const float* __restrict__ dinv,
                            float* __restrict__ qs,
                            const int* __restrict__ row,
                            const int* __restrict__ col,
                            const int* __restrict__ shoff,
                            const int* __restrict__ rank,
                            int* __restrict__ src)
{
    // f16[0,4608)  = hball (phase1) / b_out f32 8KB overlay (phase2)
    // f16[4608, 4608+4*8192) = per-wave 2-slot slice rings
    __shared__ _Float16 smem[37376];   // 74752 B

    if (blockIdx.x >= MQ_BLOCKS) {
        // ---------------- fill part (no atomics) ----------------
        const int base = (blockIdx.x - MQ_BLOCKS) * 1024 + threadIdx.x;
        #pragma unroll
        for (int u = 0; u < 4; ++u) {
            const int e = base + u * 256;
            if (e < N_EDGES_C) {
                const int c = col[e];
                const int kk = (e >> 8) & 3;
                const int slot = shoff[kk * N_NODES_C + c] + rank[e];
                src[slot] = row[e];
            }
        }
        return;
    }

    const int t    = threadIdx.x;
    const int w    = t >> 6;
    const int lane = t & 63;
    const int quad = lane >> 4;
    const int lrow = lane & 15;
    const int node0 = blockIdx.x * 64 + w * 16;
    _Float16* hb = &smem[w * 16 * XSTR];

    // ---- phase 1a: stage x -> f16 hb ----
    {
        const int n = min(node0 + lrow, N_NODES_C - 1);
        const float4* src4 = (const float4*)(xf + (size_t)n * 64 + quad * 16);
        _Float16 tmp[16];
        #pragma unroll
        for (int i = 0; i < 4; ++i) {
            const float4 v = src4[i];
            tmp[i * 4 + 0] = (_Float16)v.x;
            tmp[i * 4 + 1] = (_Float16)v.y;
            tmp[i * 4 + 2] = (_Float16)v.z;
            tmp[i * 4 + 3] = (_Float16)v.w;
        }
        *(f16x8*)&hb[lrow * XSTR + quad * 16]     = *(f16x8*)&tmp[0];
        *(f16x8*)&hb[lrow * XSTR + quad * 16 + 8] = *(f16x8*)&tmp[8];
    }

    // ---- phase 1b: 7 layers, wave-private, 16 nodes/wave ----
    {
        const _Float16* wTl = wT;
        const float* bsrc = b_in;
        for (int l = 0; l < 7; ++l) {
            const f16x8 A0 = *(const f16x8*)&hb[lrow * XSTR + quad * 8];
            const f16x8 A1 = *(const f16x8*)&hb[lrow * XSTR + 32 + quad * 8];
            #pragma unroll
            for (int Nt = 0; Nt < 4; ++Nt) {
                const f16x8 B0 = *(const f16x8*)(wTl + (Nt * 16 + lrow) * 64 + quad * 8);
                const f16x8 B1 = *(const f16x8*)(wTl + (Nt * 16 + lrow) * 64 + 32 + quad * 8);
                const float bias = bsrc[Nt * 16 + lrow];
                f32x4 C = {0.f, 0.f, 0.f, 0.f};
                C = __builtin_amdgcn_mfma_f32_16x16x32_f16(A0, B0, C, 0, 0, 0);
                C = __builtin_amdgcn_mfma_f32_16x16x32_f16(A1, B1, C, 0, 0, 0);
                #pragma unroll
                for (int r = 0; r < 4; ++r) {
                    const float v = fmaxf(C[r] + bias, 0.f);
                    hb[(quad * 4 + r) * XSTR + Nt * 16 + lrow] = (_Float16)v;
                }
            }
            wTl += 4096;
            bsrc = b_mid + (size_t)l * 64;
        }
    }

    // sync1: all hball written
    __syncthreads();

    // ---- phase 2 setup: h B-frags for ALL 4 node groups + x + dinv ----
    f16x8 Bh[4][2];
    #pragma unroll
    for (int g = 0; g < 4; ++g)
        #pragma unroll
        for (int ks = 0; ks < 2; ++ks)
            Bh[g][ks] = *(const f16x8*)&smem[g * 16 * XSTR + lrow * XSTR + ks * 32 + quad * 8];

    float4 xc[4][4];
    #pragma unroll
    for (int g = 0; g < 4; ++g) {
        const int na = min(blockIdx.x * 64 + g * 16 + lrow, N_NODES_C - 1);
        #pragma unroll
        for (int xt = 0; xt < 4; ++xt)
            xc[g][xt] = *(const float4*)(xf + (size_t)na * 64 + xt * 16 + quad * 4);
    }
    const int nself = blockIdx.x * 64 + lane;           // < N_NODES_PAD
    const float dsel = dinv[min(nself, N_NODES_C - 1)];

    // sync2: drains all lgkm/vm; hball now dead -> b_out overlay legal
    __syncthreads();

    // ---- prologue staging: bout (cooperative) + own slices 0,1 ----
    {
        float* lb = (float*)smem;
        const float* gb = b_out + (size_t)(w * 64 + lane) * 4;
        gll16(gb,        lb + w * 256);
        gll16(gb + 1024, lb + 1024 + w * 256);
        __builtin_amdgcn_sched_barrier(0);
        _Float16* ring = &smem[4608 + w * 8192];
        #pragma unroll
        for (int s = 0; s < 2; ++s) {
            const int y = s * 4 + w;
            #pragma unroll
            for (int g8 = 0; g8 < 8; ++g8)
                gll16(W3T + (size_t)y * 4096 + g8 * 512 + (size_t)lane * 8,
                      ring + s * 4096 + g8 * 512);
        }
        __builtin_amdgcn_sched_barrier(0);
    }
    asm volatile("s_waitcnt vmcnt(16)" ::: "memory");   // bout landed (slices may fly)
    __builtin_amdgcn_s_barrier();                       // bout visible to all waves
    __builtin_amdgcn_sched_barrier(0);

    const int swz = lrow & 7;
    const int cp0 = ((quad)     ^ swz) * 8;   // ks=0 chunk offset (f16)
    const int cp1 = ((4 + quad) ^ swz) * 8;   // ks=1 chunk offset
    const float* lbf = (const float*)smem;    // staged b_out (f32)
    _Float16* ring = &smem[4608 + w * 8192];

    // ---- phase 2: 8 slices/wave, wave-private ring, zero barriers ----
    #pragma unroll
    for (int yy = 0; yy < 8; ++yy) {
        if (yy == 0)      asm volatile("s_waitcnt vmcnt(8)" ::: "memory");
        else if (yy == 7) asm volatile("s_waitcnt vmcnt(1)" ::: "memory");
        else              asm volatile("s_waitcnt vmcnt(9)" ::: "memory");
        __builtin_amdgcn_sched_barrier(0);

        const int y = yy * 4 + w;
        const _Float16* cur = ring + (yy & 1) * 4096;
        float q0 = 0.f, q1 = 0.f, q2 = 0.f, q3 = 0.f;
        #pragma unroll
        for (int xt = 0; xt < 4; ++xt) {
            const _Float16* rp = cur + (xt * 16 + lrow) * 64;
            const f16x8 A0 = *(const f16x8*)(rp + cp0);
            const f16x8 A1 = *(const f16x8*)(rp + cp1);
            f32x4 C0 = {0.f,0.f,0.f,0.f}, C1 = {0.f,0.f,0.f,0.f};
            f32x4 C2 = {0.f,0.f,0.f,0.f}, C3 = {0.f,0.f,0.f,0.f};
            C0 = __builtin_amdgcn_mfma_f32_16x16x32_f16(A0, Bh[0][0], C0, 0, 0, 0);
            C0 = __builtin_amdgcn_mfma_f32_16x16x32_f16(A1, Bh[0][1], C0, 0, 0, 0);
            C1 = __builtin_amdgcn_mfma_f32_16x16x32_f16(A0, Bh[1][0], C1, 0, 0, 0);
            C1 = __builtin_amdgcn_mfma_f32_16x16x32_f16(A1, Bh[1][1], C1, 0, 0, 0);
            C2 = __builtin_amdgcn_mfma_f32_16x16x32_f16(A0, Bh[2][0], C2, 0, 0, 0);
            C2 = __builtin_amdgcn_mfma_f32_16x16x32_f16(A1, Bh[2][1], C2, 0, 0, 0);
            C3 = __builtin_amdgcn_mfma_f32_16x16x32_f16(A0, Bh[3][0], C3, 0, 0, 0);
            C3 = __builtin_amdgcn_mfma_f32_16x16x32_f16(A1, Bh[3][1], C3, 0, 0, 0);

            const float4 bf = *(const float4*)(lbf + y * 64 + xt * 16 + quad * 4);
            q0 += (C0[0] + bf.x) * xc[0][xt].x + (C0[1] + bf.y) * xc[0][xt].y
                + (C0[2] + bf.z) * xc[0][xt].z + (C0[3] + bf.w) * xc[0][xt].w;
            q1 += (C1[0] + bf.x) * xc[1][xt].x + (C1[1] + bf.y) * xc[1][xt].y
                + (C1[2] + bf.z) * xc[1][xt].z + (C1[3] + bf.w) * xc[1][xt].w;
            q2 += (C2[0] + bf.x) * xc[2][xt].x + (C2[1] + bf.y) * xc[2][xt].y
                + (C2[2] + bf.z) * xc[2][xt].z + (C2[3] + bf.w) * xc[2][xt].w;
            q3 += (C3[0] + bf.x) * xc[3][xt].x + (C3[1] + bf.y) * xc[3][xt].y
                + (C3[2] + bf.z) * xc[3][xt].z + (C3[3] + bf.w) * xc[3][xt].w;
        }
        q0 += __shfl_xor(q0, 16); q0 += __shfl_xor(q0, 32);
        q1 += __shfl_xor(q1, 16); q1 += __shfl_xor(q1, 32);
        q2 += __shfl_xor(q2, 16); q2 += __shfl_xor(q2, 32);
        q3 += __shfl_xor(q3, 16); q3 += __shfl_xor(q3, 32);

        const float qv = (quad == 0) ? q0 : (quad == 1) ? q1 : (quad == 2) ? q2 : q3;
        qs[(size_t)nself * 32 + y] = qv * dsel;         // all 64 lanes store

        __builtin_amdgcn_sched_barrier(0);
        if (yy + 2 < 8) {                               // refill just-consumed slot
            const int yn = (yy + 2) * 4 + w;
            _Float16* dst = ring + (yy & 1) * 4096;
            asm volatile("s_waitcnt lgkmcnt(0)" ::: "memory");  // slot reads drained
            __builtin_amdgcn_sched_barrier(0);
            #pragma unroll
            for (int g8 = 0; g8 < 8; ++g8)
                gll16(W3T + (size_t)yn * 4096 + g8 * 512 + (size_t)lane * 8,
                      dst + g8 * 512);
        }
        __builtin_amdgcn_sched_barrier(0);
    }
}

// ---------------------------------------------------------------------------
// Gather: out[n,y] = dinv[n] * sum_{s in CSR row n} qs[src[s], y]
// 8 threads/node, float4 per thread (32 nodes per 256-thread block).
// ---------------------------------------------------------------------------
__global__ void gather_kernel(const int* __restrict__ rowptr, const int* __restrict__ src,
                              const float* __restrict__ qs, const float* __restrict__ dinv,
                              float* __restrict__ out)
{
    const int t = threadIdx.x;
    const int node = blockIdx.x * 32 + (t >> 3);
    if (node >= N_NODES_C) return;
    const int yq = (t & 7) * 4;
    const int s0 = rowptr[node];
    const int s1 = rowptr[node + 1];
    float4 acc = {0.f, 0.f, 0.f, 0.f};
    int s = s0;
    for (; s + 4 <= s1; s += 4) {
        const int r0 = src[s], r1 = src[s + 1], r2 = src[s + 2], r3 = src[s + 3];
        const float4 a0 = *(const float4*)(qs + (size_t)r0 * 32 + yq);
        const float4 a1 = *(const float4*)(qs + (size_t)r1 * 32 + yq);
        const float4 a2 = *(const float4*)(qs + (size_t)r2 * 32 + yq);
        const float4 a3 = *(const float4*)(qs + (size_t)r3 * 32 + yq);
        acc.x += a0.x + a1.x + a2.x + a3.x;
        acc.y += a0.y + a1.y + a2.y + a3.y;
        acc.z += a0.z + a1.z + a2.z + a3.z;
        acc.w += a0.w + a1.w + a2.w + a3.w;
    }
    for (; s < s1; ++s) {
        const float4 a = *(const float4*)(qs + (size_t)src[s] * 32 + yq);
        acc.x += a.x; acc.y += a.y; acc.z += a.z; acc.w += a.w;
    }
    const float dv = dinv[node];
    float4 r;
    r.x = acc.x * dv; r.y = acc.y * dv; r.z = acc.z * dv; r.w = acc.w * dv;
    *(float4*)(out + (size_t)node * 32 + yq) = r;
}

// ---------------------------------------------------------------------------
extern "C" void kernel_launch(void* const* d_in, const int* in_sizes, int n_in,
                              void* d_out, int out_size, void* d_ws, size_t ws_size,
                              hipStream_t stream)
{
    const float* xf    = (const float*)d_in[0];
    const int*   eidx  = (const int*)d_in[1];
    const float* w_in  = (const float*)d_in[2];
    const float* b_in  = (const float*)d_in[3];
    const float* w_mid = (const float*)d_in[4];
    const float* b_mid = (const float*)d_in[5];
    const float* w_out = (const float*)d_in[6];
    const float* b_out = (const float*)d_in[7];
    float* out = (float*)d_out;

    const int* row = eidx;
    const int* col = eidx + N_EDGES_C;

    // workspace layout (bytes)
    char* ws = (char*)d_ws;
    float*    qs     = (float*)(ws + 0);             //  6,406,144 (50048 rows)
    int*      deg4   = (int*)(ws + 6406144);         //    800,000 (4 shadows)
    float*    dinv   = (float*)(ws + 7206144);       //    200,000
    _Float16* wT     = (_Float16*)(ws + 7406144);    //     57,344
    _Float16* W3T    = (_Float16*)(ws + 7463488);    //    262,144
    int*      rowptr = (int*)(ws + 7725632);         //    200,004
    int*      shoff  = (int*)(ws + 7925636);         //    800,000 (4 shadows)
    int*      rank   = (int*)(ws + 8725636);         //  3,200,000
    int*      srcb   = (int*)(ws + 11925636);        //  3,200,000
    int*      bsum   = (int*)(ws + 15125636);        //        784
    int*      boff   = (int*)(ws + 15126420);        //        784

    hipMemsetAsync(deg4, 0, 4 * N_NODES_C * sizeof(int), stream);

    prep_deg_kernel<<<dim3(624 + DEG_BLOCKS), dim3(256), 0, stream>>>(
        w_in, w_mid, w_out, col, wT, W3T, deg4, rank);

    scan1_kernel<<<dim3(196), dim3(256), 0, stream>>>(deg4, bsum);
    scan2_kernel<<<dim3(1), dim3(256), 0, stream>>>(bsum, boff, rowptr);
    scan3_kernel<<<dim3(196), dim3(256), 0, stream>>>(deg4, boff, rowptr, shoff, dinv);

    mega_kernel<<<dim3(MQ_BLOCKS + FILL_BLOCKS), dim3(256), 0, stream>>>(
        xf, b_in, b_mid, wT, W3T, b_out, dinv, qs, row, col, shoff, rank, srcb);

    gather_kernel<<<dim3(1563), dim3(256), 0, stream>>>(rowptr, srcb, qs, dinv, out);
}